// Round 1
// baseline (120.148 us; speedup 1.0000x reference)
//
#include <hip/hip_runtime.h>
#include <hip/hip_bf16.h>

#define BATCHN 512
#define NV 50
#define NE 2450
#define INSZ 16
#define MH 32
#define NH 256

typedef short s16x8 __attribute__((ext_vector_type(8)));
typedef float f32x4 __attribute__((ext_vector_type(4)));

#define PRED_OFF (BATCHN * NV * INSZ)   // 409600

// ---- ws layout (bytes) ----
// R  bf16 [B][V][3][32]  : 0        .. 4915200
// S  bf16 [B][V][3][32]  : 4915200  .. 9830400
// agg f32 [B][V][32]     : 9830400  .. 13107200
// W2t bf16 [3][32][32]   : 13107200 .. 13113344
// Wt1 bf16 [256][64]     : 13113344 .. 13146112
// Wt2 bf16 [256][256]    : 13146112 .. 13277184
// Wtmu bf16 [16][256]    : 13277184 .. 13285376   (total ~12.7 MB)

__device__ __forceinline__ unsigned short f2bf(float x) {
  unsigned int u = __float_as_uint(x);
  unsigned int r = (u + 0x7fffu + ((u >> 16) & 1u)) >> 16;  // RTNE
  return (unsigned short)r;
}
__device__ __forceinline__ float bf2f(unsigned short u) {
  return __uint_as_float(((unsigned int)u) << 16);
}
__device__ __forceinline__ unsigned int pk2(float a, float b) {
  return (unsigned int)f2bf(a) | ((unsigned int)f2bf(b) << 16);
}

// ---------------- Kernel 1: R/S precompute -------------------
// R[b,v,kk,h] = inputs[b,v,:16] @ W1[kk+1][0:16,h] + b1[kk+1][h]
// S[b,v,kk,h] = inputs[b,v,:16] @ W1[kk+1][16:32,h]
__global__ void k_rs(const float* __restrict__ inputs, const float* __restrict__ w1,
                     const float* __restrict__ b1, unsigned short* __restrict__ Rws,
                     unsigned short* __restrict__ Sws) {
  int idx = blockIdx.x * 256 + threadIdx.x;
  if (idx >= BATCHN * NV * 96) return;
  int h  = idx & 31;
  int kk = (idx >> 5) % 3;
  int bv = idx / 96;
  int k  = kk + 1;
  const float* inp = inputs + bv * INSZ;
  const float* wr  = w1 + (k * 32) * 32 + h;        // fan-in rows 0..15 (recv)
  const float* wsend = w1 + (k * 32 + 16) * 32 + h; // fan-in rows 16..31 (send)
  float r = b1[k * 32 + h];
  float s = 0.f;
#pragma unroll
  for (int c = 0; c < 16; ++c) {
    float x = inp[c];
    r += x * wr[c * 32];
    s += x * wsend[c * 32];
  }
  Rws[bv * 96 + kk * 32 + h] = f2bf(r);
  Sws[bv * 96 + kk * 32 + h] = f2bf(s);
}

// ---------------- Kernel 2: weight transpose + bf16 cast -------------------
__global__ void k_tr(const float* __restrict__ w2, const float* __restrict__ wo1,
                     const float* __restrict__ wo2, const float* __restrict__ wmu,
                     unsigned short* __restrict__ W2t, unsigned short* __restrict__ Wt1,
                     unsigned short* __restrict__ Wt2, unsigned short* __restrict__ Wtmu) {
  int idx = blockIdx.x * 256 + threadIdx.x;
  if (idx < 3072) {                      // W2t[kk][h][c] = w2[(kk+1)*32 + c][h]
    int c = idx & 31, h = (idx >> 5) & 31, kk = idx >> 10;
    W2t[idx] = f2bf(w2[((kk + 1) * 32 + c) * 32 + h]);
  } else if (idx < 3072 + 16384) {       // Wt1[n][c] (c padded 48->64 with 0)
    int j = idx - 3072; int c = j & 63, n = j >> 6;
    Wt1[j] = f2bf(c < 48 ? wo1[c * 256 + n] : 0.f);
  } else if (idx < 3072 + 16384 + 65536) { // Wt2[n][c]
    int j = idx - (3072 + 16384); int c = j & 255, n = j >> 8;
    Wt2[j] = f2bf(wo2[c * 256 + n]);
  } else if (idx < 3072 + 16384 + 65536 + 4096) { // Wtmu[n][c]
    int j = idx - (3072 + 16384 + 65536); int c = j & 255, n = j >> 8;
    Wtmu[j] = f2bf(wmu[c * 16 + n]);
  }
}

// ---------------- Kernel 3: messages + scatter to agg -------------------
// grid (B, 2); each block: batch b, receivers j in [jh*25, jh*25+25)
__global__ void k_msg(const unsigned short* __restrict__ Rws,
                      const unsigned short* __restrict__ Sws,
                      const float* __restrict__ edges, const float* __restrict__ b2,
                      const unsigned short* __restrict__ W2t, float* __restrict__ agg) {
  __shared__ unsigned short S_lds[NV * 104];  // rows padded 96->104 (2-way banks)
  __shared__ unsigned short R_lds[NV * 96];
  __shared__ float edge_lds[64 * 4];
  __shared__ float b2_lds[96];
  __shared__ float part[4][32];

  const int b   = blockIdx.x;
  const int j0  = blockIdx.y * 25;
  const int tid = threadIdx.x;
  const int w   = tid >> 6;
  const int l   = tid & 63;
  const int grp = l >> 4;         // 0..3
  const int lm  = l & 15;

  // stage R (flat) and S (row-padded) to LDS
  const uint4* Rsrc = reinterpret_cast<const uint4*>(Rws + b * 4800);
  const uint4* Ssrc = reinterpret_cast<const uint4*>(Sws + b * 4800);
  for (int i = tid; i < 600; i += 256) {
    reinterpret_cast<uint4*>(R_lds)[i] = Rsrc[i];
    int row = i / 12, ch = i % 12;
    *reinterpret_cast<uint4*>(&S_lds[row * 104 + ch * 8]) = Ssrc[i];
  }
  if (tid < 96) b2_lds[tid] = b2[32 + tid];

  // W2 B-fragments resident in registers: Bf[kk][nt]
  s16x8 Bf[3][2];
#pragma unroll
  for (int kk = 0; kk < 3; ++kk)
#pragma unroll
    for (int nt = 0; nt < 2; ++nt) {
      int h = lm + 16 * nt;
      Bf[kk][nt] = *reinterpret_cast<const s16x8*>(W2t + (kk * 32 + h) * 32 + grp * 8);
    }
  __syncthreads();

  for (int j = j0; j < j0 + 25; ++j) {
    // load edge coefficients for this receiver
    if (tid < 64) {
      int r = tid;
      float4 ev = make_float4(0.f, 0.f, 0.f, 0.f);
      if (r < 49) {
        int i = r + (r >= j ? 1 : 0);
        int e = i * 49 + (i < j ? j - 1 : j);
        ev = reinterpret_cast<const float4*>(edges)[b * NE + e];
      }
      *reinterpret_cast<float4*>(&edge_lds[r * 4]) = ev;
    }
    __syncthreads();

    // hoisted R fragment for this j (broadcast reads)
    float Rf[3][8];
#pragma unroll
    for (int kk = 0; kk < 3; ++kk) {
      s16x8 rv = *reinterpret_cast<const s16x8*>(&R_lds[j * 96 + kk * 32 + grp * 8]);
#pragma unroll
      for (int c = 0; c < 8; ++c) Rf[kk][c] = bf2f((unsigned short)rv[c]);
    }

    int r_row = 16 * w + lm;                     // edge-row this lane supplies to A
    int i_row = r_row + (r_row >= j ? 1 : 0);    // sender index (skip j)
    if (i_row > 49) i_row = 49;                  // clamp; killed by edge=0

    f32x4 zero = {0.f, 0.f, 0.f, 0.f};
    f32x4 acc[2][3];
#pragma unroll
    for (int nt = 0; nt < 2; ++nt)
#pragma unroll
      for (int kk = 0; kk < 3; ++kk) acc[nt][kk] = zero;

#pragma unroll
    for (int kk = 0; kk < 3; ++kk) {
      s16x8 sv = *reinterpret_cast<const s16x8*>(&S_lds[i_row * 104 + kk * 32 + grp * 8]);
      s16x8 af;
#pragma unroll
      for (int c = 0; c < 8; ++c) {
        float v = bf2f((unsigned short)sv[c]) + Rf[kk][c];
        v = v > 0.f ? v : 0.f;                   // h1 = relu(R + S + b1)
        af[c] = (short)f2bf(v);
      }
      acc[0][kk] = __builtin_amdgcn_mfma_f32_16x16x32_bf16(af, Bf[kk][0], acc[0][kk], 0, 0, 0);
      acc[1][kk] = __builtin_amdgcn_mfma_f32_16x16x32_bf16(af, Bf[kk][1], acc[1][kk], 0, 0, 0);
    }

    // epilogue: relu(m2 + b2) * edge, sum over this wave's 16 senders
    float s0 = 0.f, s1 = 0.f;
#pragma unroll
    for (int kk = 0; kk < 3; ++kk) {
      float bb0 = b2_lds[kk * 32 + lm];
      float bb1 = b2_lds[kk * 32 + lm + 16];
#pragma unroll
      for (int rr = 0; rr < 4; ++rr) {
        int row = 16 * w + grp * 4 + rr;         // D row = (l>>4)*4 + rr
        float E = edge_lds[row * 4 + kk + 1];
        float v0 = acc[0][kk][rr] + bb0; v0 = v0 > 0.f ? v0 : 0.f;
        float v1 = acc[1][kk][rr] + bb1; v1 = v1 > 0.f ? v1 : 0.f;
        s0 += v0 * E;
        s1 += v1 * E;
      }
    }
    s0 += __shfl_xor(s0, 16, 64); s0 += __shfl_xor(s0, 32, 64);
    s1 += __shfl_xor(s1, 16, 64); s1 += __shfl_xor(s1, 32, 64);
    if (l < 16) { part[w][l] = s0; part[w][l + 16] = s1; }
    __syncthreads();
    if (tid < 32) {
      float a = part[0][tid] + part[1][tid] + part[2][tid] + part[3][tid];
      agg[(b * NV + j) * MH + tid] = a;
    }
    __syncthreads();
  }
}

// ---------------- Kernel 4: output MLP (fc1 -> fc2 -> mu) -------------------
// grid 400 blocks x 256 thr; block handles 64 rows of (b,v)
__global__ void k_out(const float* __restrict__ inputs, const float* __restrict__ agg,
                      const unsigned short* __restrict__ Wt1, const float* __restrict__ bo1,
                      const unsigned short* __restrict__ Wt2, const float* __restrict__ bo2,
                      const unsigned short* __restrict__ Wtmu, const float* __restrict__ bmu,
                      float* __restrict__ out) {
  __shared__ unsigned short aug[64 * 72];   // [row][c] c: 0..15 inputs, 16..47 agg, 48..63 zero
  __shared__ unsigned short P1[64 * 264];   // [row][n] padded 256->264

  const int tid = threadIdx.x;
  const int w   = tid >> 6;
  const int l   = tid & 63;
  const int grp = l >> 4;
  const int lm  = l & 15;
  const int gr0 = blockIdx.x * 64;

  // build aug tile (bf16)
  {
    int row = tid >> 2, q = tid & 3;
    int gr = gr0 + row;
    float4 iv = reinterpret_cast<const float4*>(inputs)[gr * 4 + q];
    uint2 u0; u0.x = pk2(iv.x, iv.y); u0.y = pk2(iv.z, iv.w);
    *reinterpret_cast<uint2*>(&aug[row * 72 + q * 4]) = u0;
    float4 a0 = reinterpret_cast<const float4*>(agg)[gr * 8 + q * 2];
    float4 a1 = reinterpret_cast<const float4*>(agg)[gr * 8 + q * 2 + 1];
    uint4 u1; u1.x = pk2(a0.x, a0.y); u1.y = pk2(a0.z, a0.w);
    u1.z = pk2(a1.x, a1.y); u1.w = pk2(a1.z, a1.w);
    *reinterpret_cast<uint4*>(&aug[row * 72 + 16 + q * 8]) = u1;
    uint2 uz; uz.x = 0u; uz.y = 0u;
    *reinterpret_cast<uint2*>(&aug[row * 72 + 48 + q * 4]) = uz;
  }
  __syncthreads();

  const int rowA  = 16 * w + lm;    // A-fragment row
  const int kgrp  = grp * 8;        // A/B k-offset for this lane group
  const int rbase = 16 * w + grp * 4;

  // ---- fc1: aug[64x64] @ Wt1 -> P1 [64x256] ----
  f32x4 acc1[16];
#pragma unroll
  for (int nt = 0; nt < 16; ++nt) acc1[nt] = f32x4{0.f, 0.f, 0.f, 0.f};
#pragma unroll
  for (int kc = 0; kc < 2; ++kc) {
    s16x8 af = *reinterpret_cast<const s16x8*>(&aug[rowA * 72 + kc * 32 + kgrp]);
#pragma unroll
    for (int nt = 0; nt < 16; ++nt) {
      int n = lm + 16 * nt;
      s16x8 bf = *reinterpret_cast<const s16x8*>(Wt1 + n * 64 + kc * 32 + kgrp);
      acc1[nt] = __builtin_amdgcn_mfma_f32_16x16x32_bf16(af, bf, acc1[nt], 0, 0, 0);
    }
  }
#pragma unroll
  for (int nt = 0; nt < 16; ++nt) {
    int n = lm + 16 * nt;
    float bias = bo1[n];
#pragma unroll
    for (int rr = 0; rr < 4; ++rr) {
      float v = acc1[nt][rr] + bias; v = v > 0.f ? v : 0.f;
      P1[(rbase + rr) * 264 + n] = f2bf(v);
    }
  }
  // wave-local rows only -> no __syncthreads needed between stages

  // ---- fc2: P1 @ Wt2 -> pred [64x256] (write f32 out + bf16 back into P1) ----
  f32x4 acc2[16];
#pragma unroll
  for (int nt = 0; nt < 16; ++nt) acc2[nt] = f32x4{0.f, 0.f, 0.f, 0.f};
#pragma unroll
  for (int kc = 0; kc < 8; ++kc) {
    s16x8 af = *reinterpret_cast<const s16x8*>(&P1[rowA * 264 + kc * 32 + kgrp]);
#pragma unroll
    for (int nt = 0; nt < 16; ++nt) {
      int n = lm + 16 * nt;
      s16x8 bf = *reinterpret_cast<const s16x8*>(Wt2 + n * 256 + kc * 32 + kgrp);
      acc2[nt] = __builtin_amdgcn_mfma_f32_16x16x32_bf16(af, bf, acc2[nt], 0, 0, 0);
    }
  }
#pragma unroll
  for (int nt = 0; nt < 16; ++nt) {
    int n = lm + 16 * nt;
    float bias = bo2[n];
#pragma unroll
    for (int rr = 0; rr < 4; ++rr) {
      float v = acc2[nt][rr] + bias; v = v > 0.f ? v : 0.f;
      out[PRED_OFF + (gr0 + rbase + rr) * 256 + n] = v;
      P1[(rbase + rr) * 264 + n] = f2bf(v);
    }
  }

  // ---- mu: pred @ Wtmu -> [64x16] ----
  f32x4 accm = {0.f, 0.f, 0.f, 0.f};
#pragma unroll
  for (int kc = 0; kc < 8; ++kc) {
    s16x8 af = *reinterpret_cast<const s16x8*>(&P1[rowA * 264 + kc * 32 + kgrp]);
    s16x8 bf = *reinterpret_cast<const s16x8*>(Wtmu + lm * 256 + kc * 32 + kgrp);
    accm = __builtin_amdgcn_mfma_f32_16x16x32_bf16(af, bf, accm, 0, 0, 0);
  }
  {
    float bias = bmu[lm];
#pragma unroll
    for (int rr = 0; rr < 4; ++rr) {
      out[(gr0 + rbase + rr) * 16 + lm] = accm[rr] + bias;
    }
  }
}

extern "C" void kernel_launch(void* const* d_in, const int* in_sizes, int n_in,
                              void* d_out, int out_size, void* d_ws, size_t ws_size,
                              hipStream_t stream) {
  const float* inputs = (const float*)d_in[0];
  const float* edges  = (const float*)d_in[1];
  const float* w1     = (const float*)d_in[2];
  const float* b1     = (const float*)d_in[3];
  const float* w2     = (const float*)d_in[4];
  const float* b2     = (const float*)d_in[5];
  const float* wo1    = (const float*)d_in[6];
  const float* bo1    = (const float*)d_in[7];
  const float* wo2    = (const float*)d_in[8];
  const float* bo2    = (const float*)d_in[9];
  const float* wmu    = (const float*)d_in[10];
  const float* bmu    = (const float*)d_in[11];
  float* out = (float*)d_out;

  char* ws = (char*)d_ws;
  unsigned short* Rws  = (unsigned short*)(ws + 0);
  unsigned short* Sws  = (unsigned short*)(ws + 4915200);
  float*          agg  = (float*)(ws + 9830400);
  unsigned short* W2t  = (unsigned short*)(ws + 13107200);
  unsigned short* Wt1  = (unsigned short*)(ws + 13113344);
  unsigned short* Wt2  = (unsigned short*)(ws + 13146112);
  unsigned short* Wtmu = (unsigned short*)(ws + 13277184);

  k_rs<<<9600, 256, 0, stream>>>(inputs, w1, b1, Rws, Sws);
  k_tr<<<348, 256, 0, stream>>>(w2, wo1, wo2, wmu, W2t, Wt1, Wt2, Wtmu);
  k_msg<<<dim3(512, 2), 256, 0, stream>>>(Rws, Sws, edges, b2, W2t, agg);
  k_out<<<400, 256, 0, stream>>>(inputs, agg, Wt1, bo1, Wt2, bo2, Wtmu, bmu, out);
}

// Round 2
// 88.075 us; speedup vs baseline: 1.3641x; 1.3641x over previous
//
#include <hip/hip_runtime.h>
#include <hip/hip_bf16.h>

#define BATCHN 512
#define NV 50
#define NE 2450
#define INSZ 16
#define MH 32
#define NH 256

typedef short s16x8 __attribute__((ext_vector_type(8)));
typedef float f32x4 __attribute__((ext_vector_type(4)));

#define PRED_OFF (BATCHN * NV * INSZ)   // 409600

// ---- ws layout (bytes) ----
// agg  f32 [B][V][32]      : 0        .. 3276800
// W2t  bf16 [3][32][32]    : 3276800  .. 3282944
// W1t  bf16 [2][3][32][32] : 3282944  .. 3295232   (k>=16 zero-padded)
// Wt1  bf16 [256][64]      : 3295232  .. 3328000
// Wt2  bf16 [256][256]     : 3328000  .. 3459072
// Wtmu bf16 [16][256]      : 3459072  .. 3467264

__device__ __forceinline__ unsigned short f2bf(float x) {
  unsigned int u = __float_as_uint(x);
  unsigned int r = (u + 0x7fffu + ((u >> 16) & 1u)) >> 16;  // RTNE
  return (unsigned short)r;
}
__device__ __forceinline__ unsigned int pk2(float a, float b) {
  return (unsigned int)f2bf(a) | ((unsigned int)f2bf(b) << 16);
}
__device__ __forceinline__ unsigned int cvtpk(float lo, float hi) {
  unsigned int r;
  asm("v_cvt_pk_bf16_f32 %0, %1, %2" : "=v"(r) : "v"(lo), "v"(hi));
  return r;
}
__device__ __forceinline__ unsigned int pkmax0(unsigned int x, unsigned int z) {
  unsigned int r;
  asm("v_pk_max_i16 %0, %1, %2" : "=v"(r) : "v"(x), "v"(z));
  return r;
}

// ---------------- Kernel 1: weight transpose + bf16 cast -------------------
__global__ void k_tr(const float* __restrict__ w1, const float* __restrict__ w2,
                     const float* __restrict__ wo1, const float* __restrict__ wo2,
                     const float* __restrict__ wmu,
                     unsigned short* __restrict__ W2t, unsigned short* __restrict__ W1t,
                     unsigned short* __restrict__ Wt1, unsigned short* __restrict__ Wt2,
                     unsigned short* __restrict__ Wtmu) {
  int idx = blockIdx.x * 256 + threadIdx.x;
  if (idx < 3072) {                      // W2t[kk][h][c] = w2[(kk+1)*32 + c][h]
    int c = idx & 31, h = (idx >> 5) & 31, kk = idx >> 10;
    W2t[idx] = f2bf(w2[((kk + 1) * 32 + c) * 32 + h]);
  } else if (idx < 9216) {               // W1t[half][kk][n][k]
    int j = idx - 3072;
    int k = j & 31, n = (j >> 5) & 31, kk = (j >> 10) % 3, half = j / 3072;
    W1t[j] = f2bf(k < 16 ? w1[((kk + 1) * 32 + half * 16 + k) * 32 + n] : 0.f);
  } else if (idx < 9216 + 16384) {       // Wt1[n][c] (c padded 48->64 with 0)
    int j = idx - 9216; int c = j & 63, n = j >> 6;
    Wt1[j] = f2bf(c < 48 ? wo1[c * 256 + n] : 0.f);
  } else if (idx < 9216 + 16384 + 65536) { // Wt2[n][c]
    int j = idx - (9216 + 16384); int c = j & 255, n = j >> 8;
    Wt2[j] = f2bf(wo2[c * 256 + n]);
  } else if (idx < 9216 + 16384 + 65536 + 4096) { // Wtmu[n][c]
    int j = idx - (9216 + 16384 + 65536); int c = j & 255, n = j >> 8;
    Wtmu[j] = f2bf(wmu[c * 16 + n]);
  }
}

// ---------------- Kernel 2: fused fc1 + messages + scatter -------------------
// grid 512 (one block per batch), 512 threads (8 waves)
__global__ void __launch_bounds__(512, 4)
k_msg(const float* __restrict__ inputs, const float* __restrict__ edges,
      const float* __restrict__ b1, const float* __restrict__ b2,
      const unsigned short* __restrict__ W1t, const unsigned short* __restrict__ W2t,
      float* __restrict__ agg) {
  __shared__ __align__(16) float R_lds[NV * 100];  // [node][96] stride 100 f32
  __shared__ __align__(16) float S_lds[NV * 100];
  __shared__ float E_lds[NV * 64 * 3];             // [j][slot 0..63][kk]

  const int b   = blockIdx.x;
  const int tid = threadIdx.x;
  const int w   = tid >> 6;
  const int l   = tid & 63;
  const int grp = l >> 4;         // 0..3
  const int lm  = l & 15;

  // ---- stage edge coefficients (coalesced j-major gather) ----
  for (int x = tid; x < NV * 64; x += 512) {
    int r = x / 50;               // sender slot 0..63
    int j = x - r * 50;           // receiver
    float4 ev = make_float4(0.f, 0.f, 0.f, 0.f);
    if (r < 49) {
      int i = r + (r >= j ? 1 : 0);
      int e = i * 49 + j - (j > r ? 1 : 0);
      ev = reinterpret_cast<const float4*>(edges)[b * NE + e];
    }
    int base = (j * 64 + r) * 3;
    E_lds[base]     = ev.y;       // edge types 1..3 only (SKIP_FIRST)
    E_lds[base + 1] = ev.z;
    E_lds[base + 2] = ev.w;
  }

  // ---- in-block fc1 GEMM: R/S = inputs @ W1 halves (K=16 zero-padded to 32) ----
  {
    const int half = w >> 2;      // 0 = recv weights (R, +b1), 1 = send weights (S)
    const int mt   = w & 3;       // node tile
    int node  = mt * 16 + lm;
    int nodec = node < NV ? node : NV - 1;
    s16x8 af = {0, 0, 0, 0, 0, 0, 0, 0};
    if (grp < 2) {
      const float4* ip = reinterpret_cast<const float4*>(inputs) + (b * NV + nodec) * 4 + grp * 2;
      float4 x0 = ip[0], x1 = ip[1];
      union { unsigned int u[4]; s16x8 v; } U;
      U.u[0] = cvtpk(x0.x, x0.y); U.u[1] = cvtpk(x0.z, x0.w);
      U.u[2] = cvtpk(x1.x, x1.y); U.u[3] = cvtpk(x1.z, x1.w);
      af = U.v;
    }
    float* dst = half ? S_lds : R_lds;
#pragma unroll
    for (int kk = 0; kk < 3; ++kk) {
#pragma unroll
      for (int nt = 0; nt < 2; ++nt) {
        int h = lm + 16 * nt;
        s16x8 bf = *reinterpret_cast<const s16x8*>(W1t + ((half * 3 + kk) * 32 + h) * 32 + grp * 8);
        f32x4 C;
        if (half == 0) { float bv = b1[(kk + 1) * 32 + h]; C = f32x4{bv, bv, bv, bv}; }
        else C = f32x4{0.f, 0.f, 0.f, 0.f};
        f32x4 o = __builtin_amdgcn_mfma_f32_16x16x32_bf16(af, bf, C, 0, 0, 0);
#pragma unroll
        for (int rr = 0; rr < 4; ++rr) {
          int n2 = mt * 16 + grp * 4 + rr;
          if (n2 < NV) dst[n2 * 100 + kk * 32 + h] = o[rr];
        }
      }
    }
  }

  // ---- per-wave persistent fragments ----
  s16x8 Bf[3][2];                 // W2 B-frags
  f32x4 Cb[3][2];                 // fc2 bias as MFMA C operand
#pragma unroll
  for (int kk = 0; kk < 3; ++kk)
#pragma unroll
    for (int nt = 0; nt < 2; ++nt) {
      int h = lm + 16 * nt;
      Bf[kk][nt] = *reinterpret_cast<const s16x8*>(W2t + (kk * 32 + h) * 32 + grp * 8);
      float bv = b2[(kk + 1) * 32 + h];
      Cb[kk][nt] = f32x4{bv, bv, bv, bv};
    }
  const unsigned int zero = 0;
  __syncthreads();

  // ---- main loop: each wave owns receivers j = w, w+8, ... ----
  for (int j = w; j < NV; j += 8) {
    float s0 = 0.f, s1 = 0.f;
#pragma unroll
    for (int mt = 0; mt < 4; ++mt) {
      int r = mt * 16 + lm;                 // sender slot (A row)
      int i = r + (r >= j ? 1 : 0);         // sender node (skip diagonal)
      if (i > NV - 1) i = NV - 1;           // dead rows killed by E=0
      f32x4 acc[3][2];
#pragma unroll
      for (int kk = 0; kk < 3; ++kk) {
        const float* Sp = &S_lds[i * 100 + kk * 32 + grp * 8];
        const float* Rp = &R_lds[j * 100 + kk * 32 + grp * 8];
        f32x4 sA = *reinterpret_cast<const f32x4*>(Sp);
        f32x4 sB = *reinterpret_cast<const f32x4*>(Sp + 4);
        f32x4 rA = *reinterpret_cast<const f32x4*>(Rp);
        f32x4 rB = *reinterpret_cast<const f32x4*>(Rp + 4);
        union { unsigned int u[4]; s16x8 v; } U;
        U.u[0] = pkmax0(cvtpk(sA[0] + rA[0], sA[1] + rA[1]), zero);
        U.u[1] = pkmax0(cvtpk(sA[2] + rA[2], sA[3] + rA[3]), zero);
        U.u[2] = pkmax0(cvtpk(sB[0] + rB[0], sB[1] + rB[1]), zero);
        U.u[3] = pkmax0(cvtpk(sB[2] + rB[2], sB[3] + rB[3]), zero);
        acc[kk][0] = __builtin_amdgcn_mfma_f32_16x16x32_bf16(U.v, Bf[kk][0], Cb[kk][0], 0, 0, 0);
        acc[kk][1] = __builtin_amdgcn_mfma_f32_16x16x32_bf16(U.v, Bf[kk][1], Cb[kk][1], 0, 0, 0);
      }
      int slotbase = mt * 16 + grp * 4;     // D row = grp*4+rr
#pragma unroll
      for (int kk = 0; kk < 3; ++kk) {
#pragma unroll
        for (int rr = 0; rr < 4; ++rr) {
          float e = E_lds[(j * 64 + slotbase + rr) * 3 + kk];
          s0 += fmaxf(acc[kk][0][rr], 0.f) * e;
          s1 += fmaxf(acc[kk][1][rr], 0.f) * e;
        }
      }
    }
    s0 += __shfl_xor(s0, 16, 64); s0 += __shfl_xor(s0, 32, 64);
    s1 += __shfl_xor(s1, 16, 64); s1 += __shfl_xor(s1, 32, 64);
    if (l < 16)      agg[(b * NV + j) * MH + lm] = s0;
    else if (l < 32) agg[(b * NV + j) * MH + 16 + lm] = s1;
  }
}

// ---------------- Kernel 3: output MLP (fc1 -> fc2 -> mu) -------------------
// grid 400 blocks x 256 thr; block handles 64 rows of (b,v)
__global__ void k_out(const float* __restrict__ inputs, const float* __restrict__ agg,
                      const unsigned short* __restrict__ Wt1, const float* __restrict__ bo1,
                      const unsigned short* __restrict__ Wt2, const float* __restrict__ bo2,
                      const unsigned short* __restrict__ Wtmu, const float* __restrict__ bmu,
                      float* __restrict__ out) {
  __shared__ unsigned short aug[64 * 72];   // [row][c] c: 0..15 inputs, 16..47 agg, 48..63 zero
  __shared__ unsigned short P1[64 * 264];   // [row][n] padded 256->264

  const int tid = threadIdx.x;
  const int w   = tid >> 6;
  const int l   = tid & 63;
  const int grp = l >> 4;
  const int lm  = l & 15;
  const int gr0 = blockIdx.x * 64;

  // build aug tile (bf16)
  {
    int row = tid >> 2, q = tid & 3;
    int gr = gr0 + row;
    float4 iv = reinterpret_cast<const float4*>(inputs)[gr * 4 + q];
    uint2 u0; u0.x = pk2(iv.x, iv.y); u0.y = pk2(iv.z, iv.w);
    *reinterpret_cast<uint2*>(&aug[row * 72 + q * 4]) = u0;
    float4 a0 = reinterpret_cast<const float4*>(agg)[gr * 8 + q * 2];
    float4 a1 = reinterpret_cast<const float4*>(agg)[gr * 8 + q * 2 + 1];
    uint4 u1; u1.x = pk2(a0.x, a0.y); u1.y = pk2(a0.z, a0.w);
    u1.z = pk2(a1.x, a1.y); u1.w = pk2(a1.z, a1.w);
    *reinterpret_cast<uint4*>(&aug[row * 72 + 16 + q * 8]) = u1;
    uint2 uz; uz.x = 0u; uz.y = 0u;
    *reinterpret_cast<uint2*>(&aug[row * 72 + 48 + q * 4]) = uz;
  }
  __syncthreads();

  const int rowA  = 16 * w + lm;    // A-fragment row
  const int kgrp  = grp * 8;        // A/B k-offset for this lane group
  const int rbase = 16 * w + grp * 4;

  // ---- fc1: aug[64x64] @ Wt1 -> P1 [64x256] ----
  f32x4 acc1[16];
#pragma unroll
  for (int nt = 0; nt < 16; ++nt) acc1[nt] = f32x4{0.f, 0.f, 0.f, 0.f};
#pragma unroll
  for (int kc = 0; kc < 2; ++kc) {
    s16x8 af = *reinterpret_cast<const s16x8*>(&aug[rowA * 72 + kc * 32 + kgrp]);
#pragma unroll
    for (int nt = 0; nt < 16; ++nt) {
      int n = lm + 16 * nt;
      s16x8 bf = *reinterpret_cast<const s16x8*>(Wt1 + n * 64 + kc * 32 + kgrp);
      acc1[nt] = __builtin_amdgcn_mfma_f32_16x16x32_bf16(af, bf, acc1[nt], 0, 0, 0);
    }
  }
#pragma unroll
  for (int nt = 0; nt < 16; ++nt) {
    int n = lm + 16 * nt;
    float bias = bo1[n];
#pragma unroll
    for (int rr = 0; rr < 4; ++rr) {
      float v = acc1[nt][rr] + bias; v = v > 0.f ? v : 0.f;
      P1[(rbase + rr) * 264 + n] = f2bf(v);
    }
  }
  // wave-local rows only -> no __syncthreads needed between stages

  // ---- fc2: P1 @ Wt2 -> pred [64x256] (write f32 out + bf16 back into P1) ----
  f32x4 acc2[16];
#pragma unroll
  for (int nt = 0; nt < 16; ++nt) acc2[nt] = f32x4{0.f, 0.f, 0.f, 0.f};
#pragma unroll
  for (int kc = 0; kc < 8; ++kc) {
    s16x8 af = *reinterpret_cast<const s16x8*>(&P1[rowA * 264 + kc * 32 + kgrp]);
#pragma unroll
    for (int nt = 0; nt < 16; ++nt) {
      int n = lm + 16 * nt;
      s16x8 bf = *reinterpret_cast<const s16x8*>(Wt2 + n * 256 + kc * 32 + kgrp);
      acc2[nt] = __builtin_amdgcn_mfma_f32_16x16x32_bf16(af, bf, acc2[nt], 0, 0, 0);
    }
  }
#pragma unroll
  for (int nt = 0; nt < 16; ++nt) {
    int n = lm + 16 * nt;
    float bias = bo2[n];
#pragma unroll
    for (int rr = 0; rr < 4; ++rr) {
      float v = acc2[nt][rr] + bias; v = v > 0.f ? v : 0.f;
      out[PRED_OFF + (gr0 + rbase + rr) * 256 + n] = v;
      P1[(rbase + rr) * 264 + n] = f2bf(v);
    }
  }

  // ---- mu: pred @ Wtmu -> [64x16] ----
  f32x4 accm = {0.f, 0.f, 0.f, 0.f};
#pragma unroll
  for (int kc = 0; kc < 8; ++kc) {
    s16x8 af = *reinterpret_cast<const s16x8*>(&P1[rowA * 264 + kc * 32 + kgrp]);
    s16x8 bf = *reinterpret_cast<const s16x8*>(Wtmu + lm * 256 + kc * 32 + kgrp);
    accm = __builtin_amdgcn_mfma_f32_16x16x32_bf16(af, bf, accm, 0, 0, 0);
  }
  {
    float bias = bmu[lm];
#pragma unroll
    for (int rr = 0; rr < 4; ++rr) {
      out[(gr0 + rbase + rr) * 16 + lm] = accm[rr] + bias;
    }
  }
}

extern "C" void kernel_launch(void* const* d_in, const int* in_sizes, int n_in,
                              void* d_out, int out_size, void* d_ws, size_t ws_size,
                              hipStream_t stream) {
  const float* inputs = (const float*)d_in[0];
  const float* edges  = (const float*)d_in[1];
  const float* w1     = (const float*)d_in[2];
  const float* b1     = (const float*)d_in[3];
  const float* w2     = (const float*)d_in[4];
  const float* b2     = (const float*)d_in[5];
  const float* wo1    = (const float*)d_in[6];
  const float* bo1    = (const float*)d_in[7];
  const float* wo2    = (const float*)d_in[8];
  const float* bo2    = (const float*)d_in[9];
  const float* wmu    = (const float*)d_in[10];
  const float* bmu    = (const float*)d_in[11];
  float* out = (float*)d_out;

  char* ws = (char*)d_ws;
  float*          agg  = (float*)(ws + 0);
  unsigned short* W2t  = (unsigned short*)(ws + 3276800);
  unsigned short* W1t  = (unsigned short*)(ws + 3282944);
  unsigned short* Wt1  = (unsigned short*)(ws + 3295232);
  unsigned short* Wt2  = (unsigned short*)(ws + 3328000);
  unsigned short* Wtmu = (unsigned short*)(ws + 3459072);

  k_tr<<<372, 256, 0, stream>>>(w1, w2, wo1, wo2, wmu, W2t, W1t, Wt1, Wt2, Wtmu);
  k_msg<<<512, 512, 0, stream>>>(inputs, edges, b1, b2, W1t, W2t, agg);
  k_out<<<400, 256, 0, stream>>>(inputs, agg, Wt1, bo1, Wt2, bo2, Wtmu, bmu, out);
}

// Round 5
// 66.091 us; speedup vs baseline: 1.8179x; 1.3326x over previous
//
#include <hip/hip_runtime.h>
#include <hip/hip_bf16.h>

#define BATCHN 512
#define NV 50
#define NE 2450
#define INSZ 16
#define MH 32
#define NH 256

typedef short s16x8 __attribute__((ext_vector_type(8)));
typedef float f32x4 __attribute__((ext_vector_type(4)));

#define PRED_OFF (BATCHN * NV * INSZ)   // 409600

// ---- ws layout (bytes) ----
// agg    f32 [B][V][32]      : 0        .. 3276800
// W2t    bf16 [3][32][32]    : 3276800  .. 3282944
// W1t    bf16 [2][3][32][32] : 3282944  .. 3295232
// Wt1sw  bf16 16384          : 3295232  .. 3328000   (swizzled LDS image, fc1)
// Wt2sw  bf16 65536          : 3328000  .. 3459072   (4 chunks of 16384)
// Wtmusw bf16 4096           : 3459072  .. 3467264

__device__ __forceinline__ unsigned short f2bf(float x) {
  unsigned int u = __float_as_uint(x);
  unsigned int r = (u + 0x7fffu + ((u >> 16) & 1u)) >> 16;  // RTNE
  return (unsigned short)r;
}
__device__ __forceinline__ unsigned int pk2(float a, float b) {
  return (unsigned int)f2bf(a) | ((unsigned int)f2bf(b) << 16);
}
__device__ __forceinline__ unsigned int cvtpk(float lo, float hi) {
  unsigned int r;
  asm("v_cvt_pk_bf16_f32 %0, %1, %2" : "=v"(r) : "v"(lo), "v"(hi));
  return r;
}
__device__ __forceinline__ unsigned int pkmax0(unsigned int x, unsigned int z) {
  unsigned int r;
  asm("v_pk_max_i16 %0, %1, %2" : "=v"(r) : "v"(x), "v"(z));
  return r;
}

// ---------------- Kernel 1: weight transforms -------------------
__global__ void k_tr(const float* __restrict__ w1, const float* __restrict__ w2,
                     const float* __restrict__ wo1, const float* __restrict__ wo2,
                     const float* __restrict__ wmu,
                     unsigned short* __restrict__ W2t, unsigned short* __restrict__ W1t,
                     unsigned short* __restrict__ Wt1sw, unsigned short* __restrict__ Wt2sw,
                     unsigned short* __restrict__ Wtmusw) {
  int idx = blockIdx.x * 256 + threadIdx.x;
  if (idx < 3072) {                      // W2t[kk][h][c] = w2[(kk+1)*32 + c][h]
    int c = idx & 31, h = (idx >> 5) & 31, kk = idx >> 10;
    W2t[idx] = f2bf(w2[((kk + 1) * 32 + c) * 32 + h]);
  } else if (idx < 9216) {               // W1t[half][kk][n][k]
    int j = idx - 3072;
    int k = j & 31, n = (j >> 5) & 31, kk = (j >> 10) % 3, half = j / 3072;
    W1t[j] = f2bf(k < 16 ? w1[((kk + 1) * 32 + half * 16 + k) * 32 + n] : 0.f);
  } else if (idx < 9216 + 16384) {       // Wt1sw: n 0..255, kl 0..63 (48.. zero), swizzled
    int j = idx - 9216; int n = j & 255, kl = j >> 8;
    float v = kl < 48 ? wo1[kl * 256 + n] : 0.f;
    Wt1sw[n * 64 + (kl ^ ((n & 7) << 3))] = f2bf(v);
  } else if (idx < 9216 + 16384 + 65536) { // Wt2sw: 4 chunks x (n 0..255, kl 0..63)
    int j = idx - (9216 + 16384);
    int c = j >> 14, r = j & 16383;
    int n = r & 255, kl = r >> 8;
    float v = wo2[(c * 64 + kl) * 256 + n];
    Wt2sw[(c * 256 + n) * 64 + (kl ^ ((n & 7) << 3))] = f2bf(v);
  } else if (idx < 9216 + 16384 + 65536 + 4096) { // Wtmusw: n 0..15, kl 0..255
    int j = idx - (9216 + 16384 + 65536);
    int n = j & 15, kl = j >> 4;
    Wtmusw[n * 256 + (kl ^ ((n & 7) << 3))] = f2bf(wmu[kl * 16 + n]);
  }
}

// ---------------- Kernel 2: fused fc1 + messages + scatter -------------------
// grid 512 (one block per batch), 512 threads (8 waves)
// wave w: mt = w&3 (sender tile, SLOT == SENDER INDEX, held in registers), jh = w>>2
// Diagonal (sender==receiver) is killed via E=0, so the S tile is j-independent.
__global__ void __launch_bounds__(512, 4)
k_msg(const float* __restrict__ inputs, const float* __restrict__ edges,
      const float* __restrict__ b1, const float* __restrict__ b2,
      const unsigned short* __restrict__ W1t, const unsigned short* __restrict__ W2t,
      float* __restrict__ agg) {
  __shared__ __align__(16) float R_lds[NV * 100];   // f32, stride 100
  __shared__ __align__(16) float S_lds[NV * 100];   // f32, stride 100 (single-rounding)
  __shared__ __align__(16) float E_lds[NV * 156];   // [j][kk][52 slots]; slot==sender, diag/50/51 zero
  __shared__ float agg_l[NV * 32];

  const int b   = blockIdx.x;
  const int tid = threadIdx.x;
  const int w   = tid >> 6;
  const int l   = tid & 63;
  const int grp = l >> 4;         // 0..3
  const int lm  = l & 15;

  // ---- stage edge coefficients; slot r IS the sender index ----
  for (int x = tid; x < NV * 52; x += 512) {
    int r = x / 50;               // sender index 0..51
    int j = x - r * 50;           // receiver
    float4 ev = make_float4(0.f, 0.f, 0.f, 0.f);
    if (r < NV && r != j) {
      int e = r * 49 + j - (j > r ? 1 : 0);
      ev = reinterpret_cast<const float4*>(edges)[b * NE + e];
    }
    int base = j * 156 + r;
    E_lds[base]       = ev.y;     // edge types 1..3 only (SKIP_FIRST)
    E_lds[base + 52]  = ev.z;
    E_lds[base + 104] = ev.w;
  }
  for (int x = tid; x < NV * 32; x += 512) agg_l[x] = 0.f;

  // ---- in-block fc1 GEMM: R/S = inputs @ W1 halves (K=16 zero-padded to 32) ----
  {
    const int half = w >> 2;      // 0 = recv weights (R, +b1), 1 = send weights (S)
    const int mt4  = w & 3;       // node tile
    int node  = mt4 * 16 + lm;
    int nodec = node < NV ? node : NV - 1;
    s16x8 af = {0, 0, 0, 0, 0, 0, 0, 0};
    if (grp < 2) {
      const float4* ip = reinterpret_cast<const float4*>(inputs) + (b * NV + nodec) * 4 + grp * 2;
      float4 x0 = ip[0], x1 = ip[1];
      union { unsigned int u[4]; s16x8 v; } U;
      U.u[0] = cvtpk(x0.x, x0.y); U.u[1] = cvtpk(x0.z, x0.w);
      U.u[2] = cvtpk(x1.x, x1.y); U.u[3] = cvtpk(x1.z, x1.w);
      af = U.v;
    }
    float* dst = half ? S_lds : R_lds;
#pragma unroll
    for (int kk = 0; kk < 3; ++kk) {
#pragma unroll
      for (int nt = 0; nt < 2; ++nt) {
        int h = lm + 16 * nt;
        s16x8 bf = *reinterpret_cast<const s16x8*>(W1t + ((half * 3 + kk) * 32 + h) * 32 + grp * 8);
        f32x4 C;
        if (half == 0) { float bv = b1[(kk + 1) * 32 + h]; C = f32x4{bv, bv, bv, bv}; }
        else C = f32x4{0.f, 0.f, 0.f, 0.f};
        f32x4 o = __builtin_amdgcn_mfma_f32_16x16x32_bf16(af, bf, C, 0, 0, 0);
#pragma unroll
        for (int rr = 0; rr < 4; ++rr) {
          int n2 = mt4 * 16 + grp * 4 + rr;
          if (n2 < NV) dst[n2 * 100 + kk * 32 + h] = o[rr];
        }
      }
    }
  }

  // ---- per-wave persistent fragments (global reads, before barrier) ----
  s16x8 Bf[3][2];                 // W2 B-frags
  f32x4 Cb[3][2];                 // fc2 bias as MFMA C operand
#pragma unroll
  for (int kk = 0; kk < 3; ++kk)
#pragma unroll
    for (int nt = 0; nt < 2; ++nt) {
      int h = lm + 16 * nt;
      Bf[kk][nt] = *reinterpret_cast<const s16x8*>(W2t + (kk * 32 + h) * 32 + grp * 8);
      float bv = b2[(kk + 1) * 32 + h];
      Cb[kk][nt] = f32x4{bv, bv, bv, bv};
    }
  const unsigned int zero = 0;
  __syncthreads();

  // ---- load this wave's S-tile into registers (once, f32; row == sender index) ----
  const int mt = w & 3;
  const int jh = w >> 2;
  int srow = mt * 16 + lm;
  int src  = srow < NV ? srow : NV - 1;   // rows >=50 clamped; killed by E=0
  float Sreg[3][8];
#pragma unroll
  for (int kk = 0; kk < 3; ++kk) {
    const float* Sp = &S_lds[src * 100 + kk * 32 + grp * 8];
    f32x4 sA = *reinterpret_cast<const f32x4*>(Sp);
    f32x4 sB = *reinterpret_cast<const f32x4*>(Sp + 4);
#pragma unroll
    for (int p = 0; p < 4; ++p) { Sreg[kk][p] = sA[p]; Sreg[kk][4 + p] = sB[p]; }
  }

  // E-slot base for this lane; mt==3, grp>0 lanes are entirely dead (slots >= 52)
  const int sbase = mt * 16 + grp * 4;
  const bool dead = sbase > 48;
  const int sb    = dead ? 48 : sbase;

  // ---- main loop: wave handles its 16-sender tile for 25 receivers ----
  for (int j = jh * 25; j < jh * 25 + 25; ++j) {
    float s0 = 0.f, s1 = 0.f;
#pragma unroll
    for (int kk = 0; kk < 3; ++kk) {
      const float* Rp = &R_lds[j * 100 + kk * 32 + grp * 8];
      f32x4 rA = *reinterpret_cast<const f32x4*>(Rp);
      f32x4 rB = *reinterpret_cast<const f32x4*>(Rp + 4);
      union { unsigned int u[4]; s16x8 v; } U;
      U.u[0] = pkmax0(cvtpk(Sreg[kk][0] + rA[0], Sreg[kk][1] + rA[1]), zero);
      U.u[1] = pkmax0(cvtpk(Sreg[kk][2] + rA[2], Sreg[kk][3] + rA[3]), zero);
      U.u[2] = pkmax0(cvtpk(Sreg[kk][4] + rB[0], Sreg[kk][5] + rB[1]), zero);
      U.u[3] = pkmax0(cvtpk(Sreg[kk][6] + rB[2], Sreg[kk][7] + rB[3]), zero);
      f32x4 a0 = __builtin_amdgcn_mfma_f32_16x16x32_bf16(U.v, Bf[kk][0], Cb[kk][0], 0, 0, 0);
      f32x4 a1 = __builtin_amdgcn_mfma_f32_16x16x32_bf16(U.v, Bf[kk][1], Cb[kk][1], 0, 0, 0);
      f32x4 ev = *reinterpret_cast<const f32x4*>(&E_lds[j * 156 + kk * 52 + sb]);
      if (dead) ev = f32x4{0.f, 0.f, 0.f, 0.f};
#pragma unroll
      for (int rr = 0; rr < 4; ++rr) {
        s0 = fmaf(fmaxf(a0[rr], 0.f), ev[rr], s0);
        s1 = fmaf(fmaxf(a1[rr], 0.f), ev[rr], s1);
      }
    }
    s0 += __shfl_xor(s0, 16, 64); s0 += __shfl_xor(s0, 32, 64);
    s1 += __shfl_xor(s1, 16, 64); s1 += __shfl_xor(s1, 32, 64);
    if (l < 16)      atomicAdd(&agg_l[j * 32 + lm], s0);
    else if (l < 32) atomicAdd(&agg_l[j * 32 + 16 + lm], s1);
  }
  __syncthreads();
  for (int x = tid; x < NV * 32; x += 512) agg[b * (NV * 32) + x] = agg_l[x];
}

// ---------------- Kernel 3: output MLP (fc1 -> fc2 -> mu), LDS-staged B ----------
// grid 400 blocks x 256 thr; block handles 64 rows of (b,v)
__global__ void __launch_bounds__(256, 2)
k_out(const float* __restrict__ inputs, const float* __restrict__ agg,
      const unsigned short* __restrict__ Wt1sw, const float* __restrict__ bo1,
      const unsigned short* __restrict__ Wt2sw, const float* __restrict__ bo2,
      const unsigned short* __restrict__ Wtmusw, const float* __restrict__ bmu,
      float* __restrict__ out) {
  __shared__ unsigned short aug[64 * 72];   // [row][c] 0..15 inputs, 16..47 agg, 48..63 zero
  __shared__ unsigned short P1[64 * 264];   // [row][n] padded 256->264
  __shared__ __align__(16) unsigned short WB[16384]; // 32KB swizzled B chunk

  const int tid = threadIdx.x;
  const int w   = tid >> 6;
  const int l   = tid & 63;
  const int grp = l >> 4;
  const int lm  = l & 15;
  const int gr0 = blockIdx.x * 64;
  const int xo  = (lm & 7) << 3;            // lane's swizzle term (n&7 == lm&7)

  // build aug tile (bf16) + stage Wt1sw chunk
  {
    int row = tid >> 2, q = tid & 3;
    int gr = gr0 + row;
    float4 iv = reinterpret_cast<const float4*>(inputs)[gr * 4 + q];
    uint2 u0; u0.x = pk2(iv.x, iv.y); u0.y = pk2(iv.z, iv.w);
    *reinterpret_cast<uint2*>(&aug[row * 72 + q * 4]) = u0;
    float4 a0 = reinterpret_cast<const float4*>(agg)[gr * 8 + q * 2];
    float4 a1 = reinterpret_cast<const float4*>(agg)[gr * 8 + q * 2 + 1];
    uint4 u1; u1.x = pk2(a0.x, a0.y); u1.y = pk2(a0.z, a0.w);
    u1.z = pk2(a1.x, a1.y); u1.w = pk2(a1.z, a1.w);
    *reinterpret_cast<uint4*>(&aug[row * 72 + 16 + q * 8]) = u1;
    uint2 uz; uz.x = 0u; uz.y = 0u;
    *reinterpret_cast<uint2*>(&aug[row * 72 + 48 + q * 4]) = uz;
  }
  {
    const uint4* src = reinterpret_cast<const uint4*>(Wt1sw);
    for (int i = tid; i < 2048; i += 256) reinterpret_cast<uint4*>(WB)[i] = src[i];
  }
  __syncthreads();

  const int rowA  = 16 * w + lm;    // A-fragment row
  const int kgrp  = grp * 8;        // A k-offset for this lane group
  const int rbase = 16 * w + grp * 4;

  // ---- fc1: aug[64x64] @ Wt1 -> P1 [64x256] ----
  f32x4 acc1[16];
#pragma unroll
  for (int nt = 0; nt < 16; ++nt) acc1[nt] = f32x4{0.f, 0.f, 0.f, 0.f};
#pragma unroll
  for (int kc = 0; kc < 2; ++kc) {
    s16x8 af = *reinterpret_cast<const s16x8*>(&aug[rowA * 72 + kc * 32 + kgrp]);
#pragma unroll
    for (int nt = 0; nt < 16; ++nt) {
      int n = lm + 16 * nt;
      s16x8 bf = *reinterpret_cast<const s16x8*>(&WB[n * 64 + ((kc * 32 + kgrp) ^ xo)]);
      acc1[nt] = __builtin_amdgcn_mfma_f32_16x16x32_bf16(af, bf, acc1[nt], 0, 0, 0);
    }
  }
#pragma unroll
  for (int nt = 0; nt < 16; ++nt) {
    int n = lm + 16 * nt;
    float bias = bo1[n];
#pragma unroll
    for (int rr = 0; rr < 4; ++rr) {
      float v = acc1[nt][rr] + bias; v = v > 0.f ? v : 0.f;
      P1[(rbase + rr) * 264 + n] = f2bf(v);
    }
  }
  __syncthreads();   // WB (Wt1) readers done before restage

  // ---- fc2: P1 @ Wt2 (4 staged chunks) ----
  f32x4 acc2[16];
#pragma unroll
  for (int nt = 0; nt < 16; ++nt) acc2[nt] = f32x4{0.f, 0.f, 0.f, 0.f};
  for (int c = 0; c < 4; ++c) {
    const uint4* src = reinterpret_cast<const uint4*>(Wt2sw + c * 16384);
    for (int i = tid; i < 2048; i += 256) reinterpret_cast<uint4*>(WB)[i] = src[i];
    __syncthreads();
#pragma unroll
    for (int kcl = 0; kcl < 2; ++kcl) {
      int kc = c * 2 + kcl;
      s16x8 af = *reinterpret_cast<const s16x8*>(&P1[rowA * 264 + kc * 32 + kgrp]);
#pragma unroll
      for (int nt = 0; nt < 16; ++nt) {
        int n = lm + 16 * nt;
        s16x8 bf = *reinterpret_cast<const s16x8*>(&WB[n * 64 + ((kcl * 32 + kgrp) ^ xo)]);
        acc2[nt] = __builtin_amdgcn_mfma_f32_16x16x32_bf16(af, bf, acc2[nt], 0, 0, 0);
      }
    }
    __syncthreads();
  }
#pragma unroll
  for (int nt = 0; nt < 16; ++nt) {
    int n = lm + 16 * nt;
    float bias = bo2[n];
#pragma unroll
    for (int rr = 0; rr < 4; ++rr) {
      float v = acc2[nt][rr] + bias; v = v > 0.f ? v : 0.f;
      out[PRED_OFF + (gr0 + rbase + rr) * 256 + n] = v;
      P1[(rbase + rr) * 264 + n] = f2bf(v);
    }
  }

  // ---- mu: pred @ Wtmu -> [64x16] ----
  {
    const uint4* src = reinterpret_cast<const uint4*>(Wtmusw);
    for (int i = tid; i < 512; i += 256) reinterpret_cast<uint4*>(WB)[i] = src[i];
  }
  __syncthreads();
  f32x4 accm = {0.f, 0.f, 0.f, 0.f};
#pragma unroll
  for (int kc = 0; kc < 8; ++kc) {
    s16x8 af = *reinterpret_cast<const s16x8*>(&P1[rowA * 264 + kc * 32 + kgrp]);
    s16x8 bf = *reinterpret_cast<const s16x8*>(&WB[lm * 256 + ((kc * 32 + kgrp) ^ xo)]);
    accm = __builtin_amdgcn_mfma_f32_16x16x32_bf16(af, bf, accm, 0, 0, 0);
  }
  {
    float bias = bmu[lm];
#pragma unroll
    for (int rr = 0; rr < 4; ++rr) {
      out[(gr0 + rbase + rr) * 16 + lm] = accm[rr] + bias;
    }
  }
}

extern "C" void kernel_launch(void* const* d_in, const int* in_sizes, int n_in,
                              void* d_out, int out_size, void* d_ws, size_t ws_size,
                              hipStream_t stream) {
  const float* inputs = (const float*)d_in[0];
  const float* edges  = (const float*)d_in[1];
  const float* w1     = (const float*)d_in[2];
  const float* b1     = (const float*)d_in[3];
  const float* w2     = (const float*)d_in[4];
  const float* b2     = (const float*)d_in[5];
  const float* wo1    = (const float*)d_in[6];
  const float* bo1    = (const float*)d_in[7];
  const float* wo2    = (const float*)d_in[8];
  const float* bo2    = (const float*)d_in[9];
  const float* wmu    = (const float*)d_in[10];
  const float* bmu    = (const float*)d_in[11];
  float* out = (float*)d_out;

  char* ws = (char*)d_ws;
  float*          agg    = (float*)(ws + 0);
  unsigned short* W2t    = (unsigned short*)(ws + 3276800);
  unsigned short* W1t    = (unsigned short*)(ws + 3282944);
  unsigned short* Wt1sw  = (unsigned short*)(ws + 3295232);
  unsigned short* Wt2sw  = (unsigned short*)(ws + 3328000);
  unsigned short* Wtmusw = (unsigned short*)(ws + 3459072);

  k_tr<<<372, 256, 0, stream>>>(w1, w2, wo1, wo2, wmu, W2t, W1t, Wt1sw, Wt2sw, Wtmusw);
  k_msg<<<512, 512, 0, stream>>>(inputs, edges, b1, b2, W1t, W2t, agg);
  k_out<<<400, 256, 0, stream>>>(inputs, agg, Wt1sw, bo1, Wt2sw, bo2, Wtmusw, bmu, out);
}